// Round 9
// baseline (852.239 us; speedup 1.0000x reference)
//
#include <hip/hip_runtime.h>
#include <stdint.h>

// ---------- helpers ----------
typedef __attribute__((ext_vector_type(8))) short short8;   // 8 x bf16 (4 VGPRs)
typedef __attribute__((ext_vector_type(4))) float floatx4;  // MFMA accum

__device__ __forceinline__ unsigned short f2bf(float f) {
  union { float f; unsigned int u; } c; c.f = f;
  unsigned int u = c.u;
  unsigned int r = (u + 0x7fffu + ((u >> 16) & 1u)) >> 16;  // RNE
  return (unsigned short)r;
}

// async global->LDS, 16B per lane. LDS dest is wave-uniform base + lane*16
// (rule 21: LDS linear, swizzle goes on the GLOBAL source address).
__device__ __forceinline__ void load16_to_lds(const void* g, void* l) {
  __builtin_amdgcn_global_load_lds(
      (const __attribute__((address_space(1))) unsigned int*)g,
      (__attribute__((address_space(3))) unsigned int*)l, 16, 0, 0);
}

// ---------- elementwise kernels ----------
__global__ void f32_to_bf16_kernel(const float* __restrict__ in,
                                   unsigned short* __restrict__ out, long n4) {
  long i = blockIdx.x * (long)blockDim.x + threadIdx.x;
  if (i >= n4) return;
  float4 v = ((const float4*)in)[i];
  ushort4 o;
  o.x = f2bf(v.x); o.y = f2bf(v.y); o.z = f2bf(v.z); o.w = f2bf(v.w);
  ((ushort4*)out)[i] = o;
}

__global__ void dequant2_kernel(const float* __restrict__ w1q,
                                const float* __restrict__ s1,
                                const float* __restrict__ w3q,
                                const float* __restrict__ s3,
                                unsigned short* __restrict__ o1,
                                unsigned short* __restrict__ o3,
                                int K, int sK) {
  int n = blockIdx.y;
  int k = blockIdx.x * 1024 + threadIdx.x * 4;
  size_t idx = (size_t)n * K + k;
  int sidx = (n >> 7) * sK + (k >> 7);
  float sc1 = s1[sidx], sc3 = s3[sidx];
  float4 v1 = *(const float4*)(w1q + idx);
  float4 v3 = *(const float4*)(w3q + idx);
  ushort4 a, b;
  a.x = f2bf(v1.x * sc1); a.y = f2bf(v1.y * sc1);
  a.z = f2bf(v1.z * sc1); a.w = f2bf(v1.w * sc1);
  b.x = f2bf(v3.x * sc3); b.y = f2bf(v3.y * sc3);
  b.z = f2bf(v3.z * sc3); b.w = f2bf(v3.w * sc3);
  *(ushort4*)(o1 + idx) = a;
  *(ushort4*)(o3 + idx) = b;
}

__global__ void dequant1_kernel(const float* __restrict__ wq,
                                const float* __restrict__ s,
                                unsigned short* __restrict__ out,
                                int K, int sK) {
  int n = blockIdx.y;
  int k = blockIdx.x * 1024 + threadIdx.x * 4;
  size_t idx = (size_t)n * K + k;
  float sc = s[(n >> 7) * sK + (k >> 7)];
  float4 v = *(const float4*)(wq + idx);
  ushort4 o;
  o.x = f2bf(v.x * sc); o.y = f2bf(v.y * sc);
  o.z = f2bf(v.z * sc); o.w = f2bf(v.w * sc);
  *(ushort4*)(out + idx) = o;
}

// ---------- merged dual GEMM + silu (R0-proven structure) ----------
// Only change vs the measured-272us version: __launch_bounds__(256,3).
// LDS 48KB -> 3 blocks/CU (144KB <= 160KB), VGPR cap 512/3=170 (uses ~108).
// 3rd resident block overlaps the per-K-tile barrier/drain stall (m114).
__global__ __launch_bounds__(256, 3) void dual_gemm_silu(
    const unsigned short* __restrict__ A,   // [M,K] bf16 (x)
    const unsigned short* __restrict__ B1,  // [N,K] bf16 (w1)
    const unsigned short* __restrict__ B3,  // [N,K] bf16 (w3)
    unsigned short* __restrict__ C,         // [M,N] bf16 fused
    int M, int N, int K) {
  __shared__ unsigned short As[128 * 64];   // 16 KB
  __shared__ unsigned short B1s[128 * 64];  // 16 KB
  __shared__ unsigned short B3s[128 * 64];  // 16 KB

  const int tid = threadIdx.x;
  const int lane = tid & 63;
  const int wave = tid >> 6;      // 0..3
  const int wm = wave >> 1;       // 0..1  (M 64-half)
  const int wn = wave & 1;        // 0..1  (N 64-half)
  const int m0 = blockIdx.y * 128, n0 = blockIdx.x * 128;

  int soff[4];
  int sdst[4];
#pragma unroll
  for (int p = 0; p < 4; p++) {
    int u = tid + 256 * p;
    int r = u >> 3;
    int c = ((u & 7) ^ (r & 7)) * 8;
    soff[p] = r * K + c;   // pre-swizzled global source
    sdst[p] = u * 8;       // linear LDS dest
  }

  const int q = lane >> 4;        // 0..3
  const int r16 = lane & 15;
  const int rx = r16 & 7;

  floatx4 acc_g[4][4], acc_u[4][4];
#pragma unroll
  for (int i = 0; i < 4; i++)
#pragma unroll
    for (int j = 0; j < 4; j++) {
      acc_g[i][j] = (floatx4){0.f, 0.f, 0.f, 0.f};
      acc_u[i][j] = (floatx4){0.f, 0.f, 0.f, 0.f};
    }

  const unsigned short* Abase = A + (size_t)m0 * K;
  const unsigned short* B1base = B1 + (size_t)n0 * K;
  const unsigned short* B3base = B3 + (size_t)n0 * K;

  for (int k0 = 0; k0 < K; k0 += 64) {
#pragma unroll
    for (int p = 0; p < 4; p++) {
      load16_to_lds(Abase + soff[p] + k0, &As[sdst[p]]);
      load16_to_lds(B1base + soff[p] + k0, &B1s[sdst[p]]);
      load16_to_lds(B3base + soff[p] + k0, &B3s[sdst[p]]);
    }
    __syncthreads();

#pragma unroll
    for (int kh = 0; kh < 2; kh++) {
      const int kq = kh * 4 + q;          // kblk 0..7
      short8 a[4], b1v[4], b3v[4];
#pragma unroll
      for (int t = 0; t < 4; t++) {
        int row = wm * 64 + t * 16 + r16;
        a[t] = *(const short8*)&As[(row * 8 + (kq ^ rx)) * 8];
      }
#pragma unroll
      for (int j = 0; j < 4; j++) {
        int row = wn * 64 + j * 16 + r16;
        int u = (row * 8 + (kq ^ rx)) * 8;
        b1v[j] = *(const short8*)&B1s[u];
        b3v[j] = *(const short8*)&B3s[u];
      }
#pragma unroll
      for (int i = 0; i < 4; i++)
#pragma unroll
        for (int j = 0; j < 4; j++) {
          acc_g[i][j] = __builtin_amdgcn_mfma_f32_16x16x32_bf16(
              a[i], b1v[j], acc_g[i][j], 0, 0, 0);
          acc_u[i][j] = __builtin_amdgcn_mfma_f32_16x16x32_bf16(
              a[i], b3v[j], acc_u[i][j], 0, 0, 0);
        }
    }
    __syncthreads();
  }

#pragma unroll
  for (int i = 0; i < 4; i++) {
    int row0 = m0 + wm * 64 + i * 16 + q * 4;
#pragma unroll
    for (int j = 0; j < 4; j++) {
      int col = n0 + wn * 64 + j * 16 + r16;
#pragma unroll
      for (int rr = 0; rr < 4; rr++) {
        float gv = acc_g[i][j][rr];
        float uv = acc_u[i][j][rr];
        float sv = gv / (1.f + __expf(-gv)) * uv;
        C[(size_t)(row0 + rr) * N + col] = f2bf(sv);
      }
    }
  }
}

// ---------- GEMM2: 128x128 tile, BK=128 (double MFMA per tile-crossing) ----------
// Fixed-cost model (dual 884 vs gemm2 516 TF at identical per-MFMA ratios):
// per-K-tile fixed cost F ~ 4.9x the MFMA-proportional cost. BK=128 halves
// tile-crossings per MFMA: 64 MFMA + 32 ds_read + 16 gloads per tile between
// one barrier pair. LDS 2x32KB = 64KB -> still 2 blocks/CU (no m132 trap).
// Swizzle extended to 16 units/row: unit' = (u&8)|((u^row)&7) on the GLOBAL
// source (LDS linear, rule 21); read uses the same involution.
__global__ __launch_bounds__(256, 2) void gemm_nt_k128(
    const unsigned short* __restrict__ A,  // [M,K] bf16 (g)
    const unsigned short* __restrict__ B,  // [N,K] bf16 (w2)
    float* __restrict__ C,                 // [M,N] fp32
    int M, int N, int K) {
  __shared__ unsigned short As[128 * 128];  // 32 KB
  __shared__ unsigned short Bs[128 * 128];  // 32 KB

  const int tid = threadIdx.x;
  const int lane = tid & 63;
  const int wave = tid >> 6;      // 0..3
  const int wm = wave >> 1;       // 0..1
  const int wn = wave & 1;        // 0..1
  const int m0 = blockIdx.y * 128, n0 = blockIdx.x * 128;

  // 2048 16B-units per tile; 8 loads/thread. LDS dst linear (unit g),
  // global src at k-unit ug = (cu&8)|((cu^row)&7) where cu = g&15.
  int soff[8], sdst[8];
#pragma unroll
  for (int p = 0; p < 8; p++) {
    int g = tid + 256 * p;
    int r = g >> 4;
    int cu = g & 15;
    int ug = (cu & 8) | ((cu ^ (r & 7)) & 7);
    soff[p] = r * K + ug * 8;   // elements
    sdst[p] = g * 8;            // elements (linear)
  }

  const int q = lane >> 4;
  const int r16 = lane & 15;
  const int rx = r16 & 7;

  floatx4 acc[4][4];
#pragma unroll
  for (int i = 0; i < 4; i++)
#pragma unroll
    for (int j = 0; j < 4; j++) acc[i][j] = (floatx4){0.f, 0.f, 0.f, 0.f};

  const unsigned short* Abase = A + (size_t)m0 * K;
  const unsigned short* Bbase = B + (size_t)n0 * K;

  for (int k0 = 0; k0 < K; k0 += 128) {
#pragma unroll
    for (int p = 0; p < 8; p++) {
      load16_to_lds(Abase + soff[p] + k0, &As[sdst[p]]);
      load16_to_lds(Bbase + soff[p] + k0, &Bs[sdst[p]]);
    }
    __syncthreads();

#pragma unroll
    for (int kh = 0; kh < 4; kh++) {
      const int kq = kh * 4 + q;                     // k-unit 0..15
      const int ku = (kq & 8) | ((kq ^ rx) & 7);     // swizzled unit
      short8 a[4], b[4];
#pragma unroll
      for (int i = 0; i < 4; i++) {
        int row = wm * 64 + i * 16 + r16;
        a[i] = *(const short8*)&As[(row * 16 + ku) * 8];
      }
#pragma unroll
      for (int j = 0; j < 4; j++) {
        int row = wn * 64 + j * 16 + r16;
        b[j] = *(const short8*)&Bs[(row * 16 + ku) * 8];
      }
#pragma unroll
      for (int i = 0; i < 4; i++)
#pragma unroll
        for (int j = 0; j < 4; j++)
          acc[i][j] = __builtin_amdgcn_mfma_f32_16x16x32_bf16(
              a[i], b[j], acc[i][j], 0, 0, 0);
    }
    __syncthreads();
  }

#pragma unroll
  for (int i = 0; i < 4; i++) {
    int row0 = m0 + wm * 64 + i * 16 + q * 4;
#pragma unroll
    for (int j = 0; j < 4; j++) {
      int col = n0 + wn * 64 + j * 16 + r16;
#pragma unroll
      for (int rr = 0; rr < 4; rr++)
        C[(size_t)(row0 + rr) * N + col] = acc[i][j][rr];
    }
  }
}

// ---------- launch ----------
extern "C" void kernel_launch(void* const* d_in, const int* in_sizes, int n_in,
                              void* d_out, int out_size, void* d_ws, size_t ws_size,
                              hipStream_t stream) {
  const float* x = (const float*)d_in[0];
  const float* w1q = (const float*)d_in[1];
  const float* w1s = (const float*)d_in[2];
  const float* w3q = (const float*)d_in[3];
  const float* w3s = (const float*)d_in[4];
  const float* w2q = (const float*)d_in[5];
  const float* w2s = (const float*)d_in[6];

  const int T = 4096, H = 2048, F = 7168;

  char* ws = (char*)d_ws;
  unsigned short* xb  = (unsigned short*)ws;  ws += (size_t)T * H * 2;   // 16.8 MB
  unsigned short* w1b = (unsigned short*)ws;  ws += (size_t)F * H * 2;   // 29.4 MB
  unsigned short* w3b = (unsigned short*)ws;  ws += (size_t)F * H * 2;   // 29.4 MB
  unsigned short* w2b = (unsigned short*)ws;  ws += (size_t)H * F * 2;   // 29.4 MB
  unsigned short* g   = (unsigned short*)ws;  ws += (size_t)T * F * 2;   // 58.7 MB

  long xn4 = (long)T * H / 4;

  f32_to_bf16_kernel<<<(xn4 + 255) / 256, 256, 0, stream>>>(x, xb, xn4);
  dequant2_kernel<<<dim3(H / 1024, F), 256, 0, stream>>>(
      w1q, w1s, w3q, w3s, w1b, w3b, H, H / 128);
  dequant1_kernel<<<dim3(F / 1024, H), 256, 0, stream>>>(
      w2q, w2s, w2b, F, F / 128);

  // g = silu(x @ w1^T) * (x @ w3^T)
  dual_gemm_silu<<<dim3(F / 128, T / 128), 256, 0, stream>>>(xb, w1b, w3b, g, T, F, H);

  // out = g @ w2^T
  gemm_nt_k128<<<dim3(H / 128, T / 128), 256, 0, stream>>>(g, w2b, (float*)d_out, T, H, F);
}

// Round 12
// 593.459 us; speedup vs baseline: 1.4361x; 1.4361x over previous
//
#include <hip/hip_runtime.h>
#include <stdint.h>

// ---------- helpers ----------
typedef __attribute__((ext_vector_type(8))) short short8;   // 8 x bf16 (4 VGPRs)
typedef __attribute__((ext_vector_type(4))) float floatx4;  // MFMA accum

__device__ __forceinline__ unsigned short f2bf(float f) {
  union { float f; unsigned int u; } c; c.f = f;
  unsigned int u = c.u;
  unsigned int r = (u + 0x7fffu + ((u >> 16) & 1u)) >> 16;  // RNE
  return (unsigned short)r;
}

// async global->LDS, 16B per lane. LDS dest is wave-uniform base + lane*16.
__device__ __forceinline__ void load16_to_lds(const void* g, void* l) {
  __builtin_amdgcn_global_load_lds(
      (const __attribute__((address_space(1))) unsigned int*)g,
      (__attribute__((address_space(3))) unsigned int*)l, 16, 0, 0);
}

#define SBAR()   __builtin_amdgcn_s_barrier()
#define SCHED0() __builtin_amdgcn_sched_barrier(0)

// ---------- elementwise kernels ----------
__global__ void f32_to_bf16_kernel(const float* __restrict__ in,
                                   unsigned short* __restrict__ out, long n4) {
  long i = blockIdx.x * (long)blockDim.x + threadIdx.x;
  if (i >= n4) return;
  float4 v = ((const float4*)in)[i];
  ushort4 o;
  o.x = f2bf(v.x); o.y = f2bf(v.y); o.z = f2bf(v.z); o.w = f2bf(v.w);
  ((ushort4*)out)[i] = o;
}

__global__ void dequant2_kernel(const float* __restrict__ w1q,
                                const float* __restrict__ s1,
                                const float* __restrict__ w3q,
                                const float* __restrict__ s3,
                                unsigned short* __restrict__ o1,
                                unsigned short* __restrict__ o3,
                                int K, int sK) {
  int n = blockIdx.y;
  int k = blockIdx.x * 1024 + threadIdx.x * 4;
  size_t idx = (size_t)n * K + k;
  int sidx = (n >> 7) * sK + (k >> 7);
  float sc1 = s1[sidx], sc3 = s3[sidx];
  float4 v1 = *(const float4*)(w1q + idx);
  float4 v3 = *(const float4*)(w3q + idx);
  ushort4 a, b;
  a.x = f2bf(v1.x * sc1); a.y = f2bf(v1.y * sc1);
  a.z = f2bf(v1.z * sc1); a.w = f2bf(v1.w * sc1);
  b.x = f2bf(v3.x * sc3); b.y = f2bf(v3.y * sc3);
  b.z = f2bf(v3.z * sc3); b.w = f2bf(v3.w * sc3);
  *(ushort4*)(o1 + idx) = a;
  *(ushort4*)(o3 + idx) = b;
}

__global__ void dequant1_kernel(const float* __restrict__ wq,
                                const float* __restrict__ s,
                                unsigned short* __restrict__ out,
                                int K, int sK) {
  int n = blockIdx.y;
  int k = blockIdx.x * 1024 + threadIdx.x * 4;
  size_t idx = (size_t)n * K + k;
  float sc = s[(n >> 7) * sK + (k >> 7)];
  float4 v = *(const float4*)(wq + idx);
  ushort4 o;
  o.x = f2bf(v.x * sc); o.y = f2bf(v.y * sc);
  o.z = f2bf(v.z * sc); o.w = f2bf(v.w * sc);
  *(ushort4*)(out + idx) = o;
}

// ---------- merged dual GEMM + silu (R0/R2-proven: 270-272 us, 39% MfmaUtil) ----------
__global__ __launch_bounds__(256, 2) void dual_gemm_silu(
    const unsigned short* __restrict__ A,   // [M,K] bf16 (x)
    const unsigned short* __restrict__ B1,  // [N,K] bf16 (w1)
    const unsigned short* __restrict__ B3,  // [N,K] bf16 (w3)
    unsigned short* __restrict__ C,         // [M,N] bf16 fused
    int M, int N, int K) {
  __shared__ unsigned short As[128 * 64];   // 16 KB
  __shared__ unsigned short B1s[128 * 64];  // 16 KB
  __shared__ unsigned short B3s[128 * 64];  // 16 KB

  const int tid = threadIdx.x;
  const int lane = tid & 63;
  const int wave = tid >> 6;      // 0..3
  const int wm = wave >> 1;       // 0..1  (M 64-half)
  const int wn = wave & 1;        // 0..1  (N 64-half)
  const int m0 = blockIdx.y * 128, n0 = blockIdx.x * 128;

  int soff[4];
  int sdst[4];
#pragma unroll
  for (int p = 0; p < 4; p++) {
    int u = tid + 256 * p;
    int r = u >> 3;
    int c = ((u & 7) ^ (r & 7)) * 8;
    soff[p] = r * K + c;   // pre-swizzled global source
    sdst[p] = u * 8;       // linear LDS dest
  }

  const int q = lane >> 4;        // 0..3
  const int r16 = lane & 15;
  const int rx = r16 & 7;

  floatx4 acc_g[4][4], acc_u[4][4];
#pragma unroll
  for (int i = 0; i < 4; i++)
#pragma unroll
    for (int j = 0; j < 4; j++) {
      acc_g[i][j] = (floatx4){0.f, 0.f, 0.f, 0.f};
      acc_u[i][j] = (floatx4){0.f, 0.f, 0.f, 0.f};
    }

  const unsigned short* Abase = A + (size_t)m0 * K;
  const unsigned short* B1base = B1 + (size_t)n0 * K;
  const unsigned short* B3base = B3 + (size_t)n0 * K;

  for (int k0 = 0; k0 < K; k0 += 64) {
#pragma unroll
    for (int p = 0; p < 4; p++) {
      load16_to_lds(Abase + soff[p] + k0, &As[sdst[p]]);
      load16_to_lds(B1base + soff[p] + k0, &B1s[sdst[p]]);
      load16_to_lds(B3base + soff[p] + k0, &B3s[sdst[p]]);
    }
    __syncthreads();

#pragma unroll
    for (int kh = 0; kh < 2; kh++) {
      const int kq = kh * 4 + q;          // kblk 0..7
      short8 a[4], b1v[4], b3v[4];
#pragma unroll
      for (int t = 0; t < 4; t++) {
        int row = wm * 64 + t * 16 + r16;
        a[t] = *(const short8*)&As[(row * 8 + (kq ^ rx)) * 8];
      }
#pragma unroll
      for (int j = 0; j < 4; j++) {
        int row = wn * 64 + j * 16 + r16;
        int u = (row * 8 + (kq ^ rx)) * 8;
        b1v[j] = *(const short8*)&B1s[u];
        b3v[j] = *(const short8*)&B3s[u];
      }
#pragma unroll
      for (int i = 0; i < 4; i++)
#pragma unroll
        for (int j = 0; j < 4; j++) {
          acc_g[i][j] = __builtin_amdgcn_mfma_f32_16x16x32_bf16(
              a[i], b1v[j], acc_g[i][j], 0, 0, 0);
          acc_u[i][j] = __builtin_amdgcn_mfma_f32_16x16x32_bf16(
              a[i], b3v[j], acc_u[i][j], 0, 0, 0);
        }
    }
    __syncthreads();
  }

#pragma unroll
  for (int i = 0; i < 4; i++) {
    int row0 = m0 + wm * 64 + i * 16 + q * 4;
#pragma unroll
    for (int j = 0; j < 4; j++) {
      int col = n0 + wn * 64 + j * 16 + r16;
#pragma unroll
      for (int rr = 0; rr < 4; rr++) {
        float gv = acc_g[i][j][rr];
        float uv = acc_u[i][j][rr];
        float sv = gv / (1.f + __expf(-gv)) * uv;
        C[(size_t)(row0 + rr) * N + col] = f2bf(sv);
      }
    }
  }
}

// ---------- GEMM2: R2-proven 8-phase 256x256 quadrant-snake, split-K via z ----------
// R2 measured this kernel at 2.92 TF/CU (vs 2.02 for the 2-barrier 128^2) but
// launched it as TWO sequential half-GPU dispatches (128 blocks, 1 block/CU at
// 128KB LDS). Fix: one dispatch, grid (8,16,2), blockIdx.z = K-half -> 256
// blocks = full GPU, halves wall time. Kernel body byte-identical to R2
// (harness-verified correct there).
__global__ __launch_bounds__(512, 2) void gemm_nt_8p(
    const unsigned short* __restrict__ A,  // [M,Ktot] bf16
    const unsigned short* __restrict__ B,  // [N,Ktot] bf16
    float* __restrict__ Cout,              // [M,N] fp32 partial (z=0)
    float* __restrict__ Cpart,             // [M,N] fp32 partial (z=1)
    int M, int N, int Ktot, int kLen) {
  __shared__ unsigned short As[2][256 * 64];  // 64 KB
  __shared__ unsigned short Bs[2][256 * 64];  // 64 KB

  const int tid = threadIdx.x;
  const int lane = tid & 63;
  const int wave = tid >> 6;      // 0..7
  const int wm = wave >> 2;       // 0..1  (M 128-half)
  const int wn = wave & 3;        // 0..3  (N 64-quarter)
  const int m0 = blockIdx.y * 256, n0 = blockIdx.x * 256;
  const int kOff = blockIdx.z * kLen;

  int soffA[4], soffB[4], sdst[4];
#pragma unroll
  for (int p = 0; p < 4; p++) {
    int u = tid + 512 * p;
    int r = u >> 3;
    int c = ((u & 7) ^ (r & 7)) * 8;
    soffA[p] = r * Ktot + c;
    soffB[p] = r * Ktot + c;
    sdst[p] = u * 8;
  }

  const int q = lane >> 4;        // 0..3
  const int r16 = lane & 15;
  const int rx = r16 & 7;

  floatx4 acc[8][4];
#pragma unroll
  for (int i = 0; i < 8; i++)
#pragma unroll
    for (int j = 0; j < 4; j++) acc[i][j] = (floatx4){0.f, 0.f, 0.f, 0.f};

  const unsigned short* Abase = A + (size_t)m0 * Ktot + kOff;
  const unsigned short* Bbase = B + (size_t)n0 * Ktot + kOff;

  const int NT = kLen >> 6;   // 56

  // ---- prologue: tile0 fully (A0,A2,B0-3,A1,A3) + A-mh0(1) ----
  load16_to_lds(Abase + soffA[0], &As[0][sdst[0]]);
  load16_to_lds(Abase + soffA[2], &As[0][sdst[2]]);
#pragma unroll
  for (int p = 0; p < 4; p++)
    load16_to_lds(Bbase + soffB[p], &Bs[0][sdst[p]]);
  load16_to_lds(Abase + soffA[1], &As[0][sdst[1]]);
  load16_to_lds(Abase + soffA[3], &As[0][sdst[3]]);
  {
    const int k1 = (NT > 1 ? 1 : 0) * 64;
    load16_to_lds(Abase + soffA[0] + k1, &As[1][sdst[0]]);
    load16_to_lds(Abase + soffA[2] + k1, &As[1][sdst[2]]);
  }
  asm volatile("s_waitcnt vmcnt(2)" ::: "memory");  // tile0 landed
  SBAR();
  SCHED0();

  short8 a0[8], a1[8], b0[4], b1[4];

  for (int t = 0; t < NT; ++t) {
    const int cb = t & 1, nb = cb ^ 1;
    const unsigned short* Ac = As[cb];
    const unsigned short* Bc = Bs[cb];
    const int k1 = (t + 1 < NT ? t + 1 : NT - 1) << 6;
    const int k2 = (t + 2 < NT ? t + 2 : NT - 1) << 6;

    // -------- P1: a0 (mh0), b0 (nh0) -> Q00 --------
#pragma unroll
    for (int mt = 0; mt < 4; mt++) {
      int row = wm * 128 + mt * 16 + r16;
#pragma unroll
      for (int ks = 0; ks < 2; ks++) {
        int kq = ks * 4 + q;
        a0[mt * 2 + ks] = *(const short8*)&Ac[(row * 8 + (kq ^ rx)) * 8];
      }
    }
#pragma unroll
    for (int nt = 0; nt < 2; nt++) {
      int row = wn * 64 + nt * 16 + r16;
#pragma unroll
      for (int ks = 0; ks < 2; ks++) {
        int kq = ks * 4 + q;
        b0[nt * 2 + ks] = *(const short8*)&Bc[(row * 8 + (kq ^ rx)) * 8];
      }
    }
    load16_to_lds(Bbase + soffB[0] + k1, &Bs[nb][sdst[0]]);
    load16_to_lds(Bbase + soffB[1] + k1, &Bs[nb][sdst[1]]);
    SBAR();
    asm volatile("s_waitcnt lgkmcnt(0)" ::: "memory");
    SCHED0();
    __builtin_amdgcn_s_setprio(1);
#pragma unroll
    for (int mt = 0; mt < 4; mt++)
#pragma unroll
      for (int nt = 0; nt < 2; nt++)
#pragma unroll
        for (int ks = 0; ks < 2; ks++)
          acc[mt][nt] = __builtin_amdgcn_mfma_f32_16x16x32_bf16(
              a0[mt * 2 + ks], b0[nt * 2 + ks], acc[mt][nt], 0, 0, 0);
    __builtin_amdgcn_s_setprio(0);
    SBAR();

    // -------- P2: b1 (nh1) -> Q01 (reuse a0) --------
#pragma unroll
    for (int nt = 0; nt < 2; nt++) {
      int row = wn * 64 + 32 + nt * 16 + r16;
#pragma unroll
      for (int ks = 0; ks < 2; ks++) {
        int kq = ks * 4 + q;
        b1[nt * 2 + ks] = *(const short8*)&Bc[(row * 8 + (kq ^ rx)) * 8];
      }
    }
    load16_to_lds(Bbase + soffB[2] + k1, &Bs[nb][sdst[2]]);
    load16_to_lds(Bbase + soffB[3] + k1, &Bs[nb][sdst[3]]);
    SBAR();
    asm volatile("s_waitcnt lgkmcnt(0)" ::: "memory");
    SCHED0();
    __builtin_amdgcn_s_setprio(1);
#pragma unroll
    for (int mt = 0; mt < 4; mt++)
#pragma unroll
      for (int nt = 0; nt < 2; nt++)
#pragma unroll
        for (int ks = 0; ks < 2; ks++)
          acc[mt][2 + nt] = __builtin_amdgcn_mfma_f32_16x16x32_bf16(
              a0[mt * 2 + ks], b1[nt * 2 + ks], acc[mt][2 + nt], 0, 0, 0);
    __builtin_amdgcn_s_setprio(0);
    asm volatile("s_waitcnt vmcnt(5)" ::: "memory");  // A-mh1(t) landed
    SBAR();
    SCHED0();

    // -------- P3: a1 (mh1) -> Q11 (reuse b1); A-mh0 of cb now free --------
#pragma unroll
    for (int mt = 0; mt < 4; mt++) {
      int row = wm * 128 + 64 + mt * 16 + r16;
#pragma unroll
      for (int ks = 0; ks < 2; ks++) {
        int kq = ks * 4 + q;
        a1[mt * 2 + ks] = *(const short8*)&Ac[(row * 8 + (kq ^ rx)) * 8];
      }
    }
    load16_to_lds(Abase + soffA[1] + k1, &As[nb][sdst[1]]);
    load16_to_lds(Abase + soffA[0] + k2, &As[cb][sdst[0]]);
    SBAR();
    asm volatile("s_waitcnt lgkmcnt(0)" ::: "memory");
    SCHED0();
    __builtin_amdgcn_s_setprio(1);
#pragma unroll
    for (int mt = 0; mt < 4; mt++)
#pragma unroll
      for (int nt = 0; nt < 2; nt++)
#pragma unroll
        for (int ks = 0; ks < 2; ks++)
          acc[4 + mt][2 + nt] = __builtin_amdgcn_mfma_f32_16x16x32_bf16(
              a1[mt * 2 + ks], b1[nt * 2 + ks], acc[4 + mt][2 + nt], 0, 0, 0);
    __builtin_amdgcn_s_setprio(0);
    SBAR();

    // -------- P4: Q10 (reuse a1, b0) --------
    load16_to_lds(Abase + soffA[3] + k1, &As[nb][sdst[3]]);
    load16_to_lds(Abase + soffA[2] + k2, &As[cb][sdst[2]]);
    SBAR();
    SCHED0();
    __builtin_amdgcn_s_setprio(1);
#pragma unroll
    for (int mt = 0; mt < 4; mt++)
#pragma unroll
      for (int nt = 0; nt < 2; nt++)
#pragma unroll
        for (int ks = 0; ks < 2; ks++)
          acc[4 + mt][nt] = __builtin_amdgcn_mfma_f32_16x16x32_bf16(
              a1[mt * 2 + ks], b0[nt * 2 + ks], acc[4 + mt][nt], 0, 0, 0);
    __builtin_amdgcn_s_setprio(0);
    asm volatile("s_waitcnt vmcnt(4)" ::: "memory");  // B(t+1)+A-mh0(t+1) landed
    SBAR();
    SCHED0();
  }

  float* C = (blockIdx.z == 0) ? Cout : Cpart;
#pragma unroll
  for (int i = 0; i < 8; i++) {
    int row0 = m0 + wm * 128 + i * 16 + q * 4;
#pragma unroll
    for (int j = 0; j < 4; j++) {
      int col = n0 + wn * 64 + j * 16 + r16;
#pragma unroll
      for (int rr = 0; rr < 4; rr++)
        C[(size_t)(row0 + rr) * N + col] = acc[i][j][rr];
    }
  }
}

// out += part1
__global__ void add_f32_kernel(float* __restrict__ out,
                               const float* __restrict__ p1, long n4) {
  long i = blockIdx.x * (long)blockDim.x + threadIdx.x;
  if (i >= n4) return;
  float4 a = ((const float4*)out)[i];
  float4 b = ((const float4*)p1)[i];
  a.x += b.x; a.y += b.y; a.z += b.z; a.w += b.w;
  ((float4*)out)[i] = a;
}

// ---------- launch ----------
extern "C" void kernel_launch(void* const* d_in, const int* in_sizes, int n_in,
                              void* d_out, int out_size, void* d_ws, size_t ws_size,
                              hipStream_t stream) {
  const float* x = (const float*)d_in[0];
  const float* w1q = (const float*)d_in[1];
  const float* w1s = (const float*)d_in[2];
  const float* w3q = (const float*)d_in[3];
  const float* w3s = (const float*)d_in[4];
  const float* w2q = (const float*)d_in[5];
  const float* w2s = (const float*)d_in[6];

  const int T = 4096, H = 2048, F = 7168;

  char* ws = (char*)d_ws;
  unsigned short* xb  = (unsigned short*)ws;  ws += (size_t)T * H * 2;   // 16.8 MB
  unsigned short* w1b = (unsigned short*)ws;  ws += (size_t)F * H * 2;   // 29.4 MB
  unsigned short* w3b = (unsigned short*)ws;  ws += (size_t)F * H * 2;   // 29.4 MB
  unsigned short* w2b = (unsigned short*)ws;  ws += (size_t)H * F * 2;   // 29.4 MB
  unsigned short* g   = (unsigned short*)ws;  ws += (size_t)T * F * 2;   // 58.7 MB
  // part1 aliases xb+w1b (both dead after dual_gemm_silu; stream-ordered)
  float* part1 = (float*)xb;                                             // 33.5 MB

  long xn4 = (long)T * H / 4;

  f32_to_bf16_kernel<<<(xn4 + 255) / 256, 256, 0, stream>>>(x, xb, xn4);
  dequant2_kernel<<<dim3(H / 1024, F), 256, 0, stream>>>(
      w1q, w1s, w3q, w3s, w1b, w3b, H, H / 128);
  dequant1_kernel<<<dim3(F / 1024, H), 256, 0, stream>>>(
      w2q, w2s, w2b, F, F / 128);

  // g = silu(x @ w1^T) * (x @ w3^T)
  dual_gemm_silu<<<dim3(F / 128, T / 128), 256, 0, stream>>>(xb, w1b, w3b, g, T, F, H);

  // out = g @ w2^T : one full-GPU dispatch, z = K-half (256 blocks, 1/CU)
  gemm_nt_8p<<<dim3(H / 256, T / 256, 2), 512, 0, stream>>>(
      g, w2b, (float*)d_out, part1, T, H, F, F / 2);

  long on4 = (long)T * H / 4;
  add_f32_kernel<<<(on4 + 255) / 256, 256, 0, stream>>>((float*)d_out, part1, on4);
}